// Round 6
// baseline (136.877 us; speedup 1.0000x reference)
//
#include <hip/hip_runtime.h>

#define CCH   256
#define FH    96
#define FW    96
#define HW    (FH*FW)
#define SCALE 0.0625f

#define HROWS 22           // 21 data rows + 1 zeroed overflow row (aL+PSTR, weight-0)
#define PSTR  28           // LDS row stride (floats); cols 24..27 zeroed pad
#define PLANE (HROWS*PSTR) // 616 floats per wave plane
#define WCH   32           // channels per wave

// Wave-autonomous (no main-loop barriers) + depth-2 register prefetch:
// channel c's loads are issued ~2 channel-iters before their ds_write, so the
// compiler's fine-grained vmcnt leaves the newer pair in flight (R5 stalled at
// vmcnt with depth-1). All addresses clamped in-bounds by construction.
__global__ __launch_bounds__(256, 6)
void roialign_kernel(const float* __restrict__ feat,
                     const float* __restrict__ rois,
                     float* __restrict__ out)
{
    __shared__ __align__(16) float win[4 * PLANE + 8];
    __shared__ int   s_lo[2][14];
    __shared__ float s_wl[2][14], s_wh[2][14];

    const int k    = blockIdx.x >> 1;
    const int half = blockIdx.x & 1;
    const int tid  = threadIdx.x;
    const int w    = tid >> 6;
    const int ll   = tid & 63;

    // ---------- Phase A: per-roi sample coords ----------
    const float x1 = rois[k*5+1] * SCALE;
    const float y1 = rois[k*5+2] * SCALE;
    const float x2 = rois[k*5+3] * SCALE;
    const float y2 = rois[k*5+4] * SCALE;
    const int   b  = (int)rois[k*5+0];
    const float binw = fmaxf(x2 - x1, 1.0f) * (1.0f/7.0f);
    const float binh = fmaxf(y2 - y1, 1.0f) * (1.0f/7.0f);

    if (tid < 28) {
        const int   axis  = (tid >= 14) ? 1 : 0;
        const int   g     = axis ? tid - 14 : tid;
        const float start = axis ? x1 : y1;
        const float bsz   = axis ? binw : binh;
        const float offs  = (float)(g >> 1) + 0.25f + 0.5f*(float)(g & 1);
        const float coord = start + bsz * offs;
        const bool  valid = (coord >= -1.0f) && (coord <= 96.0f);
        const float cc    = fminf(fmaxf(coord, 0.0f), 95.0f);
        const float lof   = floorf(cc);
        const float frac  = cc - lof;
        const float v     = valid ? 1.0f : 0.0f;
        s_lo[axis][g] = (int)lof;
        s_wl[axis][g] = (1.0f - frac) * v;
        s_wh[axis][g] = frac * v;
    }
    __syncthreads();   // the ONLY barrier

    const int row0 = s_lo[0][0];
    const int col0 = min(s_lo[1][0] & ~3, FW - 24);
    int hw_        = min(s_lo[0][13] + 1, FH-1) - row0 + 1;
    const int hwin  = min(max(hw_, 1), 21);
    const int nslot = hwin * 6;                     // float4 slots, <=126

    float* const wp = &win[w * PLANE];

    // Zero the whole plane once: pad cols, overflow row 21, unwritten tail
    // rows must all be finite (weight-0 taps may read them).
    {
        const float4 z = make_float4(0.f, 0.f, 0.f, 0.f);
        #pragma unroll
        for (int j = 0; j < 3; ++j) {
            const int q = ll + 64*j;
            if (q < PLANE/4) *(float4*)&wp[q*4] = z;
        }
    }

    // ---------- Phase B: tap vaddrs & pre-scaled weights (channel-invariant) ----------
    const bool active = ll < 49;
    const int  p  = active ? ll : 0;
    const int  oy = p / 7;
    const int  ox = p - oy*7;

    int   aL[4];
    float w00[4], w01[4], w10[4], w11[4];
    #pragma unroll
    for (int sy = 0; sy < 2; ++sy) {
        const int   gy  = 2*oy + sy;
        const int   rlo = min(max(s_lo[0][gy] - row0, 0), HROWS-2);  // <=20
        const float wyl = s_wl[0][gy], wyh = s_wh[0][gy];
        #pragma unroll
        for (int sx = 0; sx < 2; ++sx) {
            const int   gx  = 2*ox + sx;
            const int   clo = min(max(s_lo[1][gx] - col0, 0), 23);
            const float wxl = s_wl[1][gx], wxh = s_wh[1][gx];
            const int   s   = sy*2 + sx;
            aL[s] = rlo*PSTR + clo;     // hi row = aL+PSTR always (clamp => frac=0)
            w00[s] = wyl*wxl*0.25f;  w01[s] = wyl*wxh*0.25f;
            w10[s] = wyh*wxl*0.25f;  w11[s] = wyh*wxh*0.25f;
        }
    }
    // Hoisted LDS tap pointers (constant across channels; reads at +0,+1,+PSTR,+PSTR+1)
    const float* tp0 = wp + aL[0];
    const float* tp1 = wp + aL[1];
    const float* tp2 = wp + aL[2];
    const float* tp3 = wp + aL[3];

    // ---------- load-slot constants: slots ll and ll+64 of nslot ----------
    const int  sl1 = ll + 64;
    const int  r0  = ll  / 6, q0 = ll  - r0*6;
    const int  r1  = sl1 / 6, q1 = sl1 - r1*6;
    const bool L0  = ll  < nslot;
    const bool L1  = sl1 < nslot;
    const int  goff0 = min(row0 + r0, FH-1)*FW + col0 + q0*4;   // always legal
    const int  goff1 = min(row0 + r1, FH-1)*FW + col0 + q1*4;
    const int  ld0   = min(r0, HROWS-1)*PSTR + q0*4;
    const int  ld1   = min(r1, HROWS-1)*PSTR + q1*4;

    const int    cb   = half*128 + w*WCH;
    const float* gch  = feat + (size_t)(b*CCH + cb) * HW;
    float*       outp = out  + ((size_t)k*CCH + cb)*49 + p;

    // ---------- depth-2 prefetch: set A = even channels, set B = odd ----------
    float4 a0, a1, b0, b1;
    if (L0) a0 = *(const float4*)(gch + goff0);
    if (L1) a1 = *(const float4*)(gch + goff1);
    if (L0) b0 = *(const float4*)(gch + HW + goff0);
    if (L1) b1 = *(const float4*)(gch + HW + goff1);

    for (int c = 0; c < WCH; c += 2) {
        // ---- even channel c (set A) ----
        if (L0) *(float4*)&wp[ld0] = a0;     // waits only A's loads (reg dep)
        if (L1) *(float4*)&wp[ld1] = a1;
        {
            const int pf = min(c + 2, WCH - 1);          // clamp: stay in wave's range
            const float* gp = gch + (size_t)pf * HW;
            if (L0) a0 = *(const float4*)(gp + goff0);
            if (L1) a1 = *(const float4*)(gp + goff1);
        }
        if (active) {
            float acc = w00[0]*tp0[0] + w01[0]*tp0[1] + w10[0]*tp0[PSTR] + w11[0]*tp0[PSTR+1];
            acc      += w00[1]*tp1[0] + w01[1]*tp1[1] + w10[1]*tp1[PSTR] + w11[1]*tp1[PSTR+1];
            acc      += w00[2]*tp2[0] + w01[2]*tp2[1] + w10[2]*tp2[PSTR] + w11[2]*tp2[PSTR+1];
            acc      += w00[3]*tp3[0] + w01[3]*tp3[1] + w10[3]*tp3[PSTR] + w11[3]*tp3[PSTR+1];
            outp[0] = acc;
        }
        outp += 49;

        // ---- odd channel c+1 (set B) ----
        if (L0) *(float4*)&wp[ld0] = b0;
        if (L1) *(float4*)&wp[ld1] = b1;
        {
            const int pf = min(c + 3, WCH - 1);
            const float* gp = gch + (size_t)pf * HW;
            if (L0) b0 = *(const float4*)(gp + goff0);
            if (L1) b1 = *(const float4*)(gp + goff1);
        }
        if (active) {
            float acc = w00[0]*tp0[0] + w01[0]*tp0[1] + w10[0]*tp0[PSTR] + w11[0]*tp0[PSTR+1];
            acc      += w00[1]*tp1[0] + w01[1]*tp1[1] + w10[1]*tp1[PSTR] + w11[1]*tp1[PSTR+1];
            acc      += w00[2]*tp2[0] + w01[2]*tp2[1] + w10[2]*tp2[PSTR] + w11[2]*tp2[PSTR+1];
            acc      += w00[3]*tp3[0] + w01[3]*tp3[1] + w10[3]*tp3[PSTR] + w11[3]*tp3[PSTR+1];
            outp[0] = acc;
        }
        outp += 49;
    }
}

extern "C" void kernel_launch(void* const* d_in, const int* in_sizes, int n_in,
                              void* d_out, int out_size, void* d_ws, size_t ws_size,
                              hipStream_t stream) {
    const float* feat = (const float*)d_in[0];
    const float* rois = (const float*)d_in[1];
    float*       outp = (float*)d_out;
    const int K = in_sizes[1] / 5;   // 1024
    roialign_kernel<<<K*2, 256, 0, stream>>>(feat, rois, outp);
}